// Round 5
// baseline (248.833 us; speedup 1.0000x reference)
//
#include <hip/hip_runtime.h>

// FNO spectral convolution, truncated separable DFT formulation.
// B=8, H=W=256, C_IN=C_OUT=64, modes 32 x 17 (rows fftshift-centered: k_m = m-16).
//
// ws layout (floats):
//   twA [256 w][17 n][2]  : 8704          cos/sin of 2*pi*n*w/256
//   twB [256 h][32 m][2]  : 16384         cos/sin of 2*pi*(m-16)*h/256
//   G   [B][H][17][64][2] : 4456448       W-direction DFT of x       (aliased by Z after k2a)
//   T   [B][H][17][64][2] : 4456448       mode-mixed, inverse-H DFT  (aliased by P before k2c)
//
//   P (partial xs) [8 hq][136 bn][32 m][64 i][2] = 4456448 floats -> lives in T's slot
//   Z [8 b][17 n][32 m][64 o][2] = 557056 floats               -> lives in G's slot
// Liveness: k1 writes G; k2a reads G, writes P(T); k2b reads P, writes Z(G);
//           k2c reads Z, writes T (P dead); k3 reads T. No aliasing within a kernel.

#define NB 8
#define NH 256
#define NW 256
#define NC 64
#define NM1 32
#define NM2 17

__global__ void k0_tw(float* __restrict__ twA, float* __restrict__ twB) {
    const float STEP = 0.02454369260617026f; // 2*pi/256
    int t = blockIdx.x * 256 + threadIdx.x;
    if (t < 256 * 17) {
        int w = t / 17, n = t % 17;
        int ph = (n * w) & 255;
        float ang = (float)ph * STEP;
        twA[t * 2 + 0] = cosf(ang);
        twA[t * 2 + 1] = sinf(ang);
    }
    if (t < 256 * 32) {
        int h = t >> 5, m = t & 31;
        int ph = ((m - 16) * h) & 255; // two's complement & 255 == mod 256
        float ang = (float)ph * STEP;
        twB[t * 2 + 0] = cosf(ang);
        twB[t * 2 + 1] = sinf(ang);
    }
}

// K1: per (b,h): G[n][i] = sum_w x[b,h,w,i] * e^{-2pi i n w / 256}
// 256 threads = lane i (64) x wave q (4). Each thread covers ALL 256 w for its
// n-subset {q, q+4, q+8, q+12} (+16 for q==0) -> no cross-wave reduction.
// x staged in two 32KB halves -> 5 blocks/CU (20 waves) instead of 2.
__global__ __launch_bounds__(256) void k1_fwdW(const float* __restrict__ x,
                                               const float* __restrict__ twA,
                                               float* __restrict__ G) {
    __shared__ float lds[128 * 64]; // 32 KB
    const int bh = blockIdx.x;
    const int tid = threadIdx.x;
    const int i = tid & 63;
    const int q_u = __builtin_amdgcn_readfirstlane(tid >> 6);

    float ar[5] = {0, 0, 0, 0, 0}, ai[5] = {0, 0, 0, 0, 0};
    const float4* xg = (const float4*)(x + (size_t)bh * (NW * NC));

    for (int half = 0; half < 2; ++half) {
        #pragma unroll
        for (int k = 0; k < 8; ++k) {
            int v = k * 256 + tid;              // float4 index within half
            *(float4*)&lds[v * 4] = xg[half * 2048 + v];
        }
        __syncthreads();
        #pragma unroll 2
        for (int ww = 0; ww < 128; ++ww) {
            int w = half * 128 + ww;
            float xv = lds[ww * 64 + i];
            const float* tw = twA + w * 34;     // block-uniform -> s_load
            #pragma unroll
            for (int j = 0; j < 4; ++j) {
                int nn2 = (q_u + 4 * j) * 2;
                ar[j] = fmaf(xv, tw[nn2 + 0], ar[j]);
                ai[j] = fmaf(-xv, tw[nn2 + 1], ai[j]); // e^{-i..}
            }
            if (q_u == 0) {
                ar[4] = fmaf(xv, tw[32], ar[4]);
                ai[4] = fmaf(-xv, tw[33], ai[4]);
            }
        }
        __syncthreads();
    }

    float2* G2 = (float2*)G + (size_t)bh * 17 * 64;
    #pragma unroll
    for (int j = 0; j < 4; ++j)
        G2[(q_u + 4 * j) * 64 + i] = make_float2(ar[j], ai[j]);
    if (q_u == 0)
        G2[16 * 64 + i] = make_float2(ar[4], ai[4]);
}

// K2a: partial H-DFT. grid (136 bn, 8 hq), 256 threads = lane i x wave q (8 m's each).
// P[hq][bn][m][i] = sum_{h in chunk} G[b,h,n,i] * e^{-2pi i (m-16) h/256}
__global__ __launch_bounds__(256) void k2a_hdft(const float* __restrict__ G,
                                                const float* __restrict__ twB,
                                                float* __restrict__ P) {
    const int bn = blockIdx.x;   // b*17+n
    const int b = bn / 17, n = bn % 17;
    const int hq = blockIdx.y;   // 0..7
    const int t = threadIdx.x;
    const int lane = t & 63;     // i
    const int q_u = __builtin_amdgcn_readfirstlane(t >> 6);

    float ar[8], ai[8];
    #pragma unroll
    for (int j = 0; j < 8; ++j) { ar[j] = 0.f; ai[j] = 0.f; }

    const float2* Gb = (const float2*)G + ((size_t)b * 256 * 17 + n) * 64 + lane;
    #pragma unroll 2
    for (int hh = 0; hh < 32; ++hh) {
        int h = hq * 32 + hh;
        float2 g = Gb[(size_t)h * (17 * 64)];
        const float* tw = twB + (h * 32 + q_u * 8) * 2; // wave-uniform -> s_load
        #pragma unroll
        for (int j = 0; j < 8; ++j) {
            float c = tw[2 * j], s = tw[2 * j + 1];
            ar[j] = fmaf(g.x, c, fmaf(g.y, s, ar[j]));   // conj twiddle
            ai[j] = fmaf(g.y, c, fmaf(-g.x, s, ai[j]));
        }
    }
    float2* Pp = (float2*)P + (((size_t)hq * 136 + bn) * 32 + q_u * 8) * 64 + lane;
    #pragma unroll
    for (int j = 0; j < 8; ++j) Pp[j * 64] = make_float2(ar[j], ai[j]);
}

// K2b: reduce 8 hq-partials + mode mix. grid 544 = n*32+m, 256 threads = lane o x wave q (2 b's).
// Z[b][n][m][o] = scale * sum_i xs[b,n,m,i] * (Wr + i Wi)[m,n,i,o]
__global__ __launch_bounds__(256) void k2b_mix(const float* __restrict__ P,
                                               const float* __restrict__ Wr,
                                               const float* __restrict__ Wi,
                                               float* __restrict__ Z) {
    __shared__ float2 xs[8 * 64]; // [b][i]
    const int mn = blockIdx.x;
    const int m = mn & 31, n = mn >> 5;
    const int t = threadIdx.x;
    const int lane = t & 63;
    const int q = t >> 6;

    #pragma unroll
    for (int r = 0; r < 2; ++r) {
        int v = t + r * 256;               // v = b*64 + i
        int b = v >> 6, i = v & 63;
        const float2* Pp = (const float2*)P + (((size_t)(b * 17 + n)) * 32 + m) * 64 + i;
        float re = 0.f, im = 0.f;
        #pragma unroll
        for (int hq = 0; hq < 8; ++hq) {
            float2 pv = Pp[(size_t)hq * (136 * 32 * 64)];
            re += pv.x; im += pv.y;
        }
        xs[v] = make_float2(re, im);
    }
    __syncthreads();

    const float scale = (n == 0 ? 1.0f : 2.0f) * (1.0f / 65536.0f);
    const int b0 = q * 2, b1 = b0 + 1;
    float z0r = 0, z0i = 0, z1r = 0, z1i = 0;
    const float* Wrp = Wr + (((size_t)m * 17 + n) * 64) * 64 + lane;
    const float* Wip = Wi + (((size_t)m * 17 + n) * 64) * 64 + lane;
    for (int i = 0; i < 64; ++i) {
        float wr = Wrp[(size_t)i * 64], wi = Wip[(size_t)i * 64];
        float2 x0 = xs[b0 * 64 + i], x1 = xs[b1 * 64 + i]; // LDS broadcast
        z0r = fmaf(x0.x, wr, fmaf(-x0.y, wi, z0r));
        z0i = fmaf(x0.x, wi, fmaf(x0.y, wr, z0i));
        z1r = fmaf(x1.x, wr, fmaf(-x1.y, wi, z1r));
        z1i = fmaf(x1.x, wi, fmaf(x1.y, wr, z1i));
    }
    float2* Zp = (float2*)Z;
    Zp[(((size_t)b0 * 17 + n) * 32 + m) * 64 + lane] = make_float2(z0r * scale, z0i * scale);
    Zp[(((size_t)b1 * 17 + n) * 32 + m) * 64 + lane] = make_float2(z1r * scale, z1i * scale);
}

// K2c: inverse H-DFT. grid (136 bn, 8 hq), 256 threads = lane o x wave q (8 h's each).
// T[b,h,n,o] = sum_m Z[b,n,m,o] * e^{+2pi i (m-16) h/256}
__global__ __launch_bounds__(256) void k2c_ihdft(const float* __restrict__ Z,
                                                 const float* __restrict__ twB,
                                                 float* __restrict__ T) {
    __shared__ float2 zs[32 * 64]; // [m][o], 16 KB
    const int bn = blockIdx.x;
    const int b = bn / 17, n = bn % 17;
    const int hq = blockIdx.y;
    const int t = threadIdx.x;
    const int lane = t & 63;
    const int q_u = __builtin_amdgcn_readfirstlane(t >> 6);

    const float2* Zp = (const float2*)Z + (((size_t)b * 17 + n) * 32) * 64;
    #pragma unroll
    for (int r = 0; r < 8; ++r) zs[r * 256 + t] = Zp[r * 256 + t];
    __syncthreads();

    float2* Tb = (float2*)T + ((size_t)b * 256 * 17 + n) * 64 + lane;
    #pragma unroll 2
    for (int jj = 0; jj < 8; ++jj) {
        int h = hq * 32 + q_u * 8 + jj;
        const float* tw = twB + h * 64;        // wave-uniform -> s_load
        float re0 = 0, im0 = 0, re1 = 0, im1 = 0;
        #pragma unroll
        for (int m = 0; m < 32; m += 2) {
            float2 z0 = zs[m * 64 + lane];
            float c0 = tw[2 * m + 0], s0 = tw[2 * m + 1];
            re0 = fmaf(z0.x, c0, fmaf(-z0.y, s0, re0));  // e^{+i..}
            im0 = fmaf(z0.x, s0, fmaf(z0.y, c0, im0));
            float2 z1 = zs[(m + 1) * 64 + lane];
            float c1 = tw[2 * m + 2], s1 = tw[2 * m + 3];
            re1 = fmaf(z1.x, c1, fmaf(-z1.y, s1, re1));
            im1 = fmaf(z1.x, s1, fmaf(z1.y, c1, im1));
        }
        Tb[(size_t)h * (17 * 64)] = make_float2(re0 + re1, im0 + im1);
    }
}

// K3: per (b,h): y[b,h,w,o] = sum_n Re( T[b,h,n,o] * e^{+2pi i n w/256} ); c_n folded into Z.
__global__ __launch_bounds__(256) void k3_invW(const float* __restrict__ T,
                                               const float* __restrict__ twA,
                                               float* __restrict__ y) {
    const int bh = blockIdx.x;
    const int tid = threadIdx.x;
    const int o = tid & 63;
    const int wq = tid >> 6;
    const int wq_u = __builtin_amdgcn_readfirstlane(wq);

    const float2* T2 = (const float2*)T + (size_t)bh * 17 * 64;
    float tr[17], ti[17];
    #pragma unroll
    for (int n = 0; n < 17; ++n) {
        float2 v = T2[n * 64 + o];
        tr[n] = v.x;
        ti[n] = v.y;
    }

    float* yb = y + (size_t)bh * (NW * NC);
    #pragma unroll 2
    for (int ww = 0; ww < 64; ++ww) {
        int w = wq * 64 + ww;
        const float* tw = twA + (size_t)(wq_u * 64 + ww) * 34; // uniform -> s_load
        float a0 = 0.f, a1 = 0.f, a2 = 0.f, a3 = 0.f;
        #pragma unroll
        for (int n = 0; n < 16; n += 4) {
            a0 = fmaf(tr[n + 0], tw[n * 2 + 0], a0);
            a0 = fmaf(-ti[n + 0], tw[n * 2 + 1], a0);
            a1 = fmaf(tr[n + 1], tw[n * 2 + 2], a1);
            a1 = fmaf(-ti[n + 1], tw[n * 2 + 3], a1);
            a2 = fmaf(tr[n + 2], tw[n * 2 + 4], a2);
            a2 = fmaf(-ti[n + 2], tw[n * 2 + 5], a2);
            a3 = fmaf(tr[n + 3], tw[n * 2 + 6], a3);
            a3 = fmaf(-ti[n + 3], tw[n * 2 + 7], a3);
        }
        a0 = fmaf(tr[16], tw[32], a0);
        a0 = fmaf(-ti[16], tw[33], a0);
        yb[(size_t)w * 64 + o] = (a0 + a1) + (a2 + a3);
    }
}

extern "C" void kernel_launch(void* const* d_in, const int* in_sizes, int n_in,
                              void* d_out, int out_size, void* d_ws, size_t ws_size,
                              hipStream_t stream) {
    (void)in_sizes; (void)n_in; (void)out_size; (void)ws_size;
    const float* x  = (const float*)d_in[0];
    const float* Wr = (const float*)d_in[1];
    const float* Wi = (const float*)d_in[2];
    float* out = (float*)d_out;
    float* ws  = (float*)d_ws;

    float* twA = ws;                 // 8704 floats
    float* twB = ws + 8704;          // 16384 floats
    float* G   = ws + 25088;         // 4456448 floats
    float* T   = G + 4456448;        // 4456448 floats
    float* P   = T;                  // alias: partials live in T's slot (same size)
    float* Z   = G;                  // alias: Z (2.2 MB) lives in dead G's slot

    k0_tw<<<32, 256, 0, stream>>>(twA, twB);
    k1_fwdW<<<NB * NH, 256, 0, stream>>>(x, twA, G);
    k2a_hdft<<<dim3(NB * NM2, 8), 256, 0, stream>>>(G, twB, P);
    k2b_mix<<<NM1 * NM2, 256, 0, stream>>>(P, Wr, Wi, Z);
    k2c_ihdft<<<dim3(NB * NM2, 8), 256, 0, stream>>>(Z, twB, T);
    k3_invW<<<NB * NH, 256, 0, stream>>>(T, twA, out);
}

// Round 6
// 160.545 us; speedup vs baseline: 1.5499x; 1.5499x over previous
//
#include <hip/hip_runtime.h>

// FNO spectral convolution, truncated separable DFT formulation.
// B=8, H=W=256, C_IN=C_OUT=64, modes 32 x 17 (rows fftshift-centered: k_m = m-16).
//
// ws layout (floats):
//   twA [256 w][17 n][2]  : 8704          cos/sin of 2*pi*n*w/256
//   twB [256 h][32 m][2]  : 16384         cos/sin of 2*pi*(m-16)*h/256
//   G   [B][H][17][64][2] : 4456448       W-direction DFT of x       (aliased by Z after k2a)
//   T   [B][H][17][64][2] : 4456448       mode-mixed, inverse-H DFT  (aliased by P before k2c)
//
//   P (partial xs) [8 hq][136 bn][32 m][64 i][2] = 4456448 floats -> lives in T's slot
//   Z [8 b][17 n][32 m][64 o][2] = 557056 floats                  -> lives in G's slot
// Liveness: k1 writes G; k2a reads G, writes P(T); k2b reads P, writes Z(G);
//           k2c reads Z, writes T (P dead); k3 reads T. No aliasing within a kernel.

#define NB 8
#define NH 256
#define NW 256
#define NC 64
#define NM1 32
#define NM2 17

__global__ void k0_tw(float* __restrict__ twA, float* __restrict__ twB) {
    const float STEP = 0.02454369260617026f; // 2*pi/256
    int t = blockIdx.x * 256 + threadIdx.x;
    if (t < 256 * 17) {
        int w = t / 17, n = t % 17;
        int ph = (n * w) & 255;
        float ang = (float)ph * STEP;
        twA[t * 2 + 0] = cosf(ang);
        twA[t * 2 + 1] = sinf(ang);
    }
    if (t < 256 * 32) {
        int h = t >> 5, m = t & 31;
        int ph = ((m - 16) * h) & 255; // two's complement & 255 == mod 256
        float ang = (float)ph * STEP;
        twB[t * 2 + 0] = cosf(ang);
        twB[t * 2 + 1] = sinf(ang);
    }
}

// K1: per (b,h): G[n][i] = sum_w x[b,h,w,i] * e^{-2pi i n w / 256}
// 256 threads = lane i (64) x wave wq (4 w-quarters). Each thread accumulates
// ALL 17 n's for its 64-w quarter: 68 fma per s_load batch of 34 twiddle floats
// (dense enough to hide SMEM latency). x loaded DIRECTLY from global (no reuse
// within block -> staging was pure overhead). LDS only for the 4-way cross-wave
// reduce, [q][n][i] layout -> stride-1 lanes, conflict-free. 34.8 KB -> 4 blocks/CU.
__global__ __launch_bounds__(256) void k1_fwdW(const float* __restrict__ x,
                                               const float* __restrict__ twA,
                                               float* __restrict__ G) {
    __shared__ float lre[4][17][64];
    __shared__ float lim[4][17][64];
    const int bh = blockIdx.x;
    const int tid = threadIdx.x;
    const int i = tid & 63;
    const int wq_u = __builtin_amdgcn_readfirstlane(tid >> 6);

    float ar[17], ai[17];
    #pragma unroll
    for (int n = 0; n < 17; ++n) { ar[n] = 0.f; ai[n] = 0.f; }

    const float* xb = x + (size_t)bh * (NW * NC) + (size_t)wq_u * 64 * 64 + i;
    #pragma unroll 2
    for (int ww = 0; ww < 64; ++ww) {
        float xv = xb[(size_t)ww * 64];              // coalesced 256B/wave, independent
        const float* tw = twA + (wq_u * 64 + ww) * 34; // wave-uniform -> s_load
        #pragma unroll
        for (int n = 0; n < 17; ++n) {
            ar[n] = fmaf(xv, tw[n * 2 + 0], ar[n]);
            ai[n] = fmaf(-xv, tw[n * 2 + 1], ai[n]); // e^{-i..}
        }
    }

    #pragma unroll
    for (int n = 0; n < 17; ++n) {
        lre[wq_u][n][i] = ar[n];                     // stride-1 lanes: conflict-free
        lim[wq_u][n][i] = ai[n];
    }
    __syncthreads();

    float2* G2 = (float2*)G + (size_t)bh * 17 * 64;
    for (int n = wq_u; n < 17; n += 4) {
        float re = (lre[0][n][i] + lre[1][n][i]) + (lre[2][n][i] + lre[3][n][i]);
        float im = (lim[0][n][i] + lim[1][n][i]) + (lim[2][n][i] + lim[3][n][i]);
        G2[n * 64 + i] = make_float2(re, im);
    }
}

// K2a: partial H-DFT. grid (136 bn, 8 hq), 256 threads = lane i x wave q (8 m's each).
// P[hq][bn][m][i] = sum_{h in chunk} G[b,h,n,i] * e^{-2pi i (m-16) h/256}
__global__ __launch_bounds__(256) void k2a_hdft(const float* __restrict__ G,
                                                const float* __restrict__ twB,
                                                float* __restrict__ P) {
    const int bn = blockIdx.x;   // b*17+n
    const int b = bn / 17, n = bn % 17;
    const int hq = blockIdx.y;   // 0..7
    const int t = threadIdx.x;
    const int lane = t & 63;     // i
    const int q_u = __builtin_amdgcn_readfirstlane(t >> 6);

    float ar[8], ai[8];
    #pragma unroll
    for (int j = 0; j < 8; ++j) { ar[j] = 0.f; ai[j] = 0.f; }

    const float2* Gb = (const float2*)G + ((size_t)b * 256 * 17 + n) * 64 + lane;
    #pragma unroll 2
    for (int hh = 0; hh < 32; ++hh) {
        int h = hq * 32 + hh;
        float2 g = Gb[(size_t)h * (17 * 64)];
        const float* tw = twB + (h * 32 + q_u * 8) * 2; // wave-uniform -> s_load
        #pragma unroll
        for (int j = 0; j < 8; ++j) {
            float c = tw[2 * j], s = tw[2 * j + 1];
            ar[j] = fmaf(g.x, c, fmaf(g.y, s, ar[j]));   // conj twiddle
            ai[j] = fmaf(g.y, c, fmaf(-g.x, s, ai[j]));
        }
    }
    float2* Pp = (float2*)P + (((size_t)hq * 136 + bn) * 32 + q_u * 8) * 64 + lane;
    #pragma unroll
    for (int j = 0; j < 8; ++j) Pp[j * 64] = make_float2(ar[j], ai[j]);
}

// K2b: reduce 8 hq-partials + mode mix. grid 544 = n*32+m, 256 threads = lane o x wave q (2 b's).
// Z[b][n][m][o] = scale * sum_i xs[b,n,m,i] * (Wr + i Wi)[m,n,i,o]
__global__ __launch_bounds__(256) void k2b_mix(const float* __restrict__ P,
                                               const float* __restrict__ Wr,
                                               const float* __restrict__ Wi,
                                               float* __restrict__ Z) {
    __shared__ float2 xs[8 * 64]; // [b][i]
    const int mn = blockIdx.x;
    const int m = mn & 31, n = mn >> 5;
    const int t = threadIdx.x;
    const int lane = t & 63;
    const int q = t >> 6;

    #pragma unroll
    for (int r = 0; r < 2; ++r) {
        int v = t + r * 256;               // v = b*64 + i
        int b = v >> 6, i = v & 63;
        const float2* Pp = (const float2*)P + (((size_t)(b * 17 + n)) * 32 + m) * 64 + i;
        float re = 0.f, im = 0.f;
        #pragma unroll
        for (int hq = 0; hq < 8; ++hq) {
            float2 pv = Pp[(size_t)hq * (136 * 32 * 64)];
            re += pv.x; im += pv.y;
        }
        xs[v] = make_float2(re, im);
    }
    __syncthreads();

    const float scale = (n == 0 ? 1.0f : 2.0f) * (1.0f / 65536.0f);
    const int b0 = q * 2, b1 = b0 + 1;
    float z0r = 0, z0i = 0, z1r = 0, z1i = 0;
    const float* Wrp = Wr + (((size_t)m * 17 + n) * 64) * 64 + lane;
    const float* Wip = Wi + (((size_t)m * 17 + n) * 64) * 64 + lane;
    for (int i = 0; i < 64; ++i) {
        float wr = Wrp[(size_t)i * 64], wi = Wip[(size_t)i * 64];
        float2 x0 = xs[b0 * 64 + i], x1 = xs[b1 * 64 + i]; // LDS broadcast
        z0r = fmaf(x0.x, wr, fmaf(-x0.y, wi, z0r));
        z0i = fmaf(x0.x, wi, fmaf(x0.y, wr, z0i));
        z1r = fmaf(x1.x, wr, fmaf(-x1.y, wi, z1r));
        z1i = fmaf(x1.x, wi, fmaf(x1.y, wr, z1i));
    }
    float2* Zp = (float2*)Z;
    Zp[(((size_t)b0 * 17 + n) * 32 + m) * 64 + lane] = make_float2(z0r * scale, z0i * scale);
    Zp[(((size_t)b1 * 17 + n) * 32 + m) * 64 + lane] = make_float2(z1r * scale, z1i * scale);
}

// K2c: inverse H-DFT. grid (136 bn, 8 hq), 256 threads = lane o x wave q (8 h's each).
// T[b,h,n,o] = sum_m Z[b,n,m,o] * e^{+2pi i (m-16) h/256}
__global__ __launch_bounds__(256) void k2c_ihdft(const float* __restrict__ Z,
                                                 const float* __restrict__ twB,
                                                 float* __restrict__ T) {
    __shared__ float2 zs[32 * 64]; // [m][o], 16 KB
    const int bn = blockIdx.x;
    const int b = bn / 17, n = bn % 17;
    const int hq = blockIdx.y;
    const int t = threadIdx.x;
    const int lane = t & 63;
    const int q_u = __builtin_amdgcn_readfirstlane(t >> 6);

    const float2* Zp = (const float2*)Z + (((size_t)b * 17 + n) * 32) * 64;
    #pragma unroll
    for (int r = 0; r < 8; ++r) zs[r * 256 + t] = Zp[r * 256 + t];
    __syncthreads();

    float2* Tb = (float2*)T + ((size_t)b * 256 * 17 + n) * 64 + lane;
    #pragma unroll 2
    for (int jj = 0; jj < 8; ++jj) {
        int h = hq * 32 + q_u * 8 + jj;
        const float* tw = twB + h * 64;        // wave-uniform -> s_load
        float re0 = 0, im0 = 0, re1 = 0, im1 = 0;
        #pragma unroll
        for (int m = 0; m < 32; m += 2) {
            float2 z0 = zs[m * 64 + lane];
            float c0 = tw[2 * m + 0], s0 = tw[2 * m + 1];
            re0 = fmaf(z0.x, c0, fmaf(-z0.y, s0, re0));  // e^{+i..}
            im0 = fmaf(z0.x, s0, fmaf(z0.y, c0, im0));
            float2 z1 = zs[(m + 1) * 64 + lane];
            float c1 = tw[2 * m + 2], s1 = tw[2 * m + 3];
            re1 = fmaf(z1.x, c1, fmaf(-z1.y, s1, re1));
            im1 = fmaf(z1.x, s1, fmaf(z1.y, c1, im1));
        }
        Tb[(size_t)h * (17 * 64)] = make_float2(re0 + re1, im0 + im1);
    }
}

// K3: per (b,h): y[b,h,w,o] = sum_n Re( T[b,h,n,o] * e^{+2pi i n w/256} ); c_n folded into Z.
__global__ __launch_bounds__(256) void k3_invW(const float* __restrict__ T,
                                               const float* __restrict__ twA,
                                               float* __restrict__ y) {
    const int bh = blockIdx.x;
    const int tid = threadIdx.x;
    const int o = tid & 63;
    const int wq = tid >> 6;
    const int wq_u = __builtin_amdgcn_readfirstlane(wq);

    const float2* T2 = (const float2*)T + (size_t)bh * 17 * 64;
    float tr[17], ti[17];
    #pragma unroll
    for (int n = 0; n < 17; ++n) {
        float2 v = T2[n * 64 + o];
        tr[n] = v.x;
        ti[n] = v.y;
    }

    float* yb = y + (size_t)bh * (NW * NC);
    #pragma unroll 2
    for (int ww = 0; ww < 64; ++ww) {
        int w = wq * 64 + ww;
        const float* tw = twA + (size_t)(wq_u * 64 + ww) * 34; // uniform -> s_load
        float a0 = 0.f, a1 = 0.f, a2 = 0.f, a3 = 0.f;
        #pragma unroll
        for (int n = 0; n < 16; n += 4) {
            a0 = fmaf(tr[n + 0], tw[n * 2 + 0], a0);
            a0 = fmaf(-ti[n + 0], tw[n * 2 + 1], a0);
            a1 = fmaf(tr[n + 1], tw[n * 2 + 2], a1);
            a1 = fmaf(-ti[n + 1], tw[n * 2 + 3], a1);
            a2 = fmaf(tr[n + 2], tw[n * 2 + 4], a2);
            a2 = fmaf(-ti[n + 2], tw[n * 2 + 5], a2);
            a3 = fmaf(tr[n + 3], tw[n * 2 + 6], a3);
            a3 = fmaf(-ti[n + 3], tw[n * 2 + 7], a3);
        }
        a0 = fmaf(tr[16], tw[32], a0);
        a0 = fmaf(-ti[16], tw[33], a0);
        yb[(size_t)w * 64 + o] = (a0 + a1) + (a2 + a3);
    }
}

extern "C" void kernel_launch(void* const* d_in, const int* in_sizes, int n_in,
                              void* d_out, int out_size, void* d_ws, size_t ws_size,
                              hipStream_t stream) {
    (void)in_sizes; (void)n_in; (void)out_size; (void)ws_size;
    const float* x  = (const float*)d_in[0];
    const float* Wr = (const float*)d_in[1];
    const float* Wi = (const float*)d_in[2];
    float* out = (float*)d_out;
    float* ws  = (float*)d_ws;

    float* twA = ws;                 // 8704 floats
    float* twB = ws + 8704;          // 16384 floats
    float* G   = ws + 25088;         // 4456448 floats
    float* T   = G + 4456448;        // 4456448 floats
    float* P   = T;                  // alias: partials live in T's slot (same size)
    float* Z   = G;                  // alias: Z (2.2 MB) lives in dead G's slot

    k0_tw<<<32, 256, 0, stream>>>(twA, twB);
    k1_fwdW<<<NB * NH, 256, 0, stream>>>(x, twA, G);
    k2a_hdft<<<dim3(NB * NM2, 8), 256, 0, stream>>>(G, twB, P);
    k2b_mix<<<NM1 * NM2, 256, 0, stream>>>(P, Wr, Wi, Z);
    k2c_ihdft<<<dim3(NB * NM2, 8), 256, 0, stream>>>(Z, twB, T);
    k3_invW<<<NB * NH, 256, 0, stream>>>(T, twA, out);
}